// Round 5
// baseline (546.306 us; speedup 1.0000x reference)
//
#include <hip/hip_runtime.h>

#define N_NODES 50000
#define N_EDGES 600000
#define HID 128
#define N_GRAPHS 512
#define BN_EPS 1e-5f

// ---------------------------------------------------------------------------
// CSR build
// ---------------------------------------------------------------------------
__global__ void deg_count_kernel(const int* __restrict__ dst, int* __restrict__ deg, int nE) {
    int e = blockIdx.x * blockDim.x + threadIdx.x;
    if (e < nE) atomicAdd(&deg[dst[e]], 1);
}

__global__ __launch_bounds__(256) void alloc_kernel(int* __restrict__ cursor,
                                                    int* __restrict__ row_beg,
                                                    float* __restrict__ inv_deg,
                                                    int* __restrict__ total, int n) {
    __shared__ int tmp[256];
    __shared__ int base;
    int i = blockIdx.x * 256 + threadIdx.x;
    int d = (i < n) ? cursor[i] : 0;
    tmp[threadIdx.x] = d;
    __syncthreads();
#pragma unroll
    for (int off = 1; off < 256; off <<= 1) {
        int v = (threadIdx.x >= off) ? tmp[threadIdx.x - off] : 0;
        __syncthreads();
        tmp[threadIdx.x] += v;
        __syncthreads();
    }
    if (threadIdx.x == 255) base = atomicAdd(total, tmp[255]);
    __syncthreads();
    if (i < n) {
        int b = base + tmp[threadIdx.x] - d;
        row_beg[i] = b;
        cursor[i] = b;
        inv_deg[i] = 1.0f / fmaxf((float)d, 1.0f);
    }
}

__global__ void csr_fill_kernel(const int* __restrict__ src, const int* __restrict__ dst,
                                int* __restrict__ cursor, int* __restrict__ csr_src, int nE) {
    int e = blockIdx.x * blockDim.x + threadIdx.x;
    if (e < nE) {
        int pos = atomicAdd(&cursor[dst[e]], 1);
        csr_src[pos] = src[e];
    }
}

// ---------------------------------------------------------------------------
// gather aggregation; AFF: apply y = relu(v*cs[col]+sh[col]) to gathered rows
// ---------------------------------------------------------------------------
template<bool AFF>
__global__ void csr_aggregate_kernel(const float* __restrict__ feat,
                                     const int* __restrict__ row_beg,
                                     const int* __restrict__ row_end,
                                     const int* __restrict__ csr_src,
                                     const float* __restrict__ cs,
                                     const float* __restrict__ sh,
                                     float* __restrict__ agg, int n) {
    int gid = blockIdx.x * blockDim.x + threadIdx.x;
    int node = gid >> 5;
    int lane = gid & 31;
    if (node >= n) return;
    int beg = row_beg[node];
    int end = row_end[node];
    float4 cs4 = make_float4(0.f,0.f,0.f,0.f), sh4 = cs4;
    if (AFF) {
        cs4 = *(const float4*)(cs + lane * 4);
        sh4 = *(const float4*)(sh + lane * 4);
    }
    float4 acc = make_float4(0.f, 0.f, 0.f, 0.f);
    int e = beg;
    for (; e + 1 < end; e += 2) {
        int s0 = csr_src[e];
        int s1 = csr_src[e + 1];
        float4 v0 = ((const float4*)(feat + (size_t)s0 * HID))[lane];
        float4 v1 = ((const float4*)(feat + (size_t)s1 * HID))[lane];
        if (AFF) {
            v0.x = fmaxf(v0.x * cs4.x + sh4.x, 0.f); v1.x = fmaxf(v1.x * cs4.x + sh4.x, 0.f);
            v0.y = fmaxf(v0.y * cs4.y + sh4.y, 0.f); v1.y = fmaxf(v1.y * cs4.y + sh4.y, 0.f);
            v0.z = fmaxf(v0.z * cs4.z + sh4.z, 0.f); v1.z = fmaxf(v1.z * cs4.z + sh4.z, 0.f);
            v0.w = fmaxf(v0.w * cs4.w + sh4.w, 0.f); v1.w = fmaxf(v1.w * cs4.w + sh4.w, 0.f);
        }
        acc.x += v0.x + v1.x;
        acc.y += v0.y + v1.y;
        acc.z += v0.z + v1.z;
        acc.w += v0.w + v1.w;
    }
    if (e < end) {
        int s0 = csr_src[e];
        float4 v0 = ((const float4*)(feat + (size_t)s0 * HID))[lane];
        if (AFF) {
            v0.x = fmaxf(v0.x * cs4.x + sh4.x, 0.f);
            v0.y = fmaxf(v0.y * cs4.y + sh4.y, 0.f);
            v0.z = fmaxf(v0.z * cs4.z + sh4.z, 0.f);
            v0.w = fmaxf(v0.w * cs4.w + sh4.w, 0.f);
        }
        acc.x += v0.x; acc.y += v0.y; acc.z += v0.z; acc.w += v0.w;
    }
    ((float4*)(agg + (size_t)node * HID))[lane] = acc;
}

// ---------------------------------------------------------------------------
// 64x128-tile GEMM, 128 threads, per-thread 8 rows x 8 cols.
// Thread cols: {colg*4..+3} and {64+colg*4..+3}  (colg = t&15) -> bank-clean
// b128 reads (each 16-lane phase sweeps all 32 banks, 2-way = free).
// Thread rows: rowg*8..+7 (rowg = t>>4, 0..7).
// As: [64 rows][32 k] pad 33;  Ws: [32 k][128 cols].
//
// MODE 0 (fused GIN):  T1 = relu((A1+A2) @ W1 + b1);  C = T1 @ W2 + b2
// MODE 2 (SAGE):       C = (A1*scale) @ W1 + act(A2) @ W2 + b1
//                      act(v) = AFFB ? relu(v*csB+shB) : v
// STATS: accumulate column sum/sumsq of C into stats[0:128]/[128:256]
// ---------------------------------------------------------------------------
template<int MODE, bool STATS, bool AFFB>
__global__ __launch_bounds__(128, 2) void gemm_tile_kernel(
    const float* __restrict__ A1, const float* __restrict__ A2,
    const float* __restrict__ W1, const float* __restrict__ W2,
    const float* __restrict__ b1, const float* __restrict__ b2,
    const float* __restrict__ scale,
    const float* __restrict__ csB, const float* __restrict__ shB,
    float* __restrict__ stats, float* __restrict__ C, int M)
{
    __shared__ float As[64 * 33];
    __shared__ float Ws[32 * 128];

    const int t = threadIdx.x;
    const int colg = t & 15;
    const int cA = colg * 4;         // cols cA..cA+3   (regs 0..3)
    const int cB = 64 + colg * 4;    // cols cB..cB+3   (regs 4..7)
    const int rowg = t >> 4;         // 0..7
    const int row0r = rowg * 8;
    const int row0 = blockIdx.x * 64;

    float acc[8][8];
#pragma unroll
    for (int j = 0; j < 8; j++)
#pragma unroll
        for (int c = 0; c < 8; c++) acc[j][c] = 0.f;

    // =================== phase 1: A-from-global @ W1 ===================
    for (int kc = 0; kc < 128; kc += 32) {
        // stage A: 512 float4, 4 per thread
#pragma unroll
        for (int i = 0; i < 4; i++) {
            int f4 = t + i * 128;
            int r = f4 >> 3;
            int c4 = f4 & 7;
            int grow = row0 + r;
            float4 v = make_float4(0.f, 0.f, 0.f, 0.f);
            if (grow < M) {
                v = *(const float4*)(A1 + (size_t)grow * 128 + kc + c4 * 4);
                if (MODE == 0) {
                    float4 v2 = *(const float4*)(A2 + (size_t)grow * 128 + kc + c4 * 4);
                    v.x += v2.x; v.y += v2.y; v.z += v2.z; v.w += v2.w;
                } else {
                    float sc = scale[grow];
                    v.x *= sc; v.y *= sc; v.z *= sc; v.w *= sc;
                }
            }
            float* p = As + r * 33 + c4 * 4;
            p[0] = v.x; p[1] = v.y; p[2] = v.z; p[3] = v.w;
        }
        // stage W1 chunk: 1024 float4, 8 per thread
#pragma unroll
        for (int i = 0; i < 8; i++) {
            int f4 = t + i * 128;
            int wr = f4 >> 5;
            int wc = f4 & 31;
            ((float4*)Ws)[wr * 32 + wc] = ((const float4*)(W1 + (size_t)(kc + wr) * 128))[wc];
        }
        __syncthreads();
#pragma unroll 2
        for (int k = 0; k < 32; k++) {
            float4 bb0 = *(const float4*)(Ws + k * 128 + cA);
            float4 bb1 = *(const float4*)(Ws + k * 128 + cB);
            float bv[8] = {bb0.x, bb0.y, bb0.z, bb0.w, bb1.x, bb1.y, bb1.z, bb1.w};
#pragma unroll
            for (int j = 0; j < 8; j++) {
                float a = As[(row0r + j) * 33 + k];
#pragma unroll
                for (int c = 0; c < 8; c++) acc[j][c] += a * bv[c];
            }
        }
        __syncthreads();
    }

    float out[8][8];

    if (MODE == 0) {
        // T1 = relu(acc + b1)
        float4 bs0 = *(const float4*)(b1 + cA);
        float4 bs1 = *(const float4*)(b1 + cB);
        float bv[8] = {bs0.x, bs0.y, bs0.z, bs0.w, bs1.x, bs1.y, bs1.z, bs1.w};
#pragma unroll
        for (int j = 0; j < 8; j++)
#pragma unroll
            for (int c = 0; c < 8; c++) acc[j][c] = fmaxf(acc[j][c] + bv[c], 0.f);

        // =================== phase 2: T1 @ W2 (T1 chunks from registers) ===
        float acc2[8][8];
#pragma unroll
        for (int j = 0; j < 8; j++)
#pragma unroll
            for (int c = 0; c < 8; c++) acc2[j][c] = 0.f;

        for (int p = 0; p < 4; p++) {
            // writers: threads owning cols [32p, 32p+32)
            bool lowhalf = (p < 2);
            int pg = lowhalf ? p : (p - 2);
            if ((colg >> 3) == pg) {
                int lc = (colg & 7) * 4;
                int rb = lowhalf ? 0 : 4;
#pragma unroll
                for (int j = 0; j < 8; j++) {
                    float* q = As + (row0r + j) * 33 + lc;
#pragma unroll
                    for (int c = 0; c < 4; c++) q[c] = acc[j][rb + c];
                }
            }
#pragma unroll
            for (int i = 0; i < 8; i++) {
                int f4 = t + i * 128;
                int wr = f4 >> 5;
                int wc = f4 & 31;
                ((float4*)Ws)[wr * 32 + wc] = ((const float4*)(W2 + (size_t)(p * 32 + wr) * 128))[wc];
            }
            __syncthreads();
#pragma unroll 2
            for (int k = 0; k < 32; k++) {
                float4 bb0 = *(const float4*)(Ws + k * 128 + cA);
                float4 bb1 = *(const float4*)(Ws + k * 128 + cB);
                float bv2[8] = {bb0.x, bb0.y, bb0.z, bb0.w, bb1.x, bb1.y, bb1.z, bb1.w};
#pragma unroll
                for (int j = 0; j < 8; j++) {
                    float a = As[(row0r + j) * 33 + k];
#pragma unroll
                    for (int c = 0; c < 8; c++) acc2[j][c] += a * bv2[c];
                }
            }
            __syncthreads();
        }
        float4 c0 = *(const float4*)(b2 + cA);
        float4 c1 = *(const float4*)(b2 + cB);
        float bv2[8] = {c0.x, c0.y, c0.z, c0.w, c1.x, c1.y, c1.z, c1.w};
#pragma unroll
        for (int j = 0; j < 8; j++)
#pragma unroll
            for (int c = 0; c < 8; c++) out[j][c] = acc2[j][c] + bv2[c];
    } else {
        // =================== phase 2: act(A2) @ W2 ===================
        for (int kc = 0; kc < 128; kc += 32) {
#pragma unroll
            for (int i = 0; i < 4; i++) {
                int f4 = t + i * 128;
                int r = f4 >> 3;
                int c4 = f4 & 7;
                int grow = row0 + r;
                float4 v = make_float4(0.f, 0.f, 0.f, 0.f);
                if (grow < M) {
                    v = *(const float4*)(A2 + (size_t)grow * 128 + kc + c4 * 4);
                    if (AFFB) {
                        float4 cs4 = *(const float4*)(csB + kc + c4 * 4);
                        float4 sh4 = *(const float4*)(shB + kc + c4 * 4);
                        v.x = fmaxf(v.x * cs4.x + sh4.x, 0.f);
                        v.y = fmaxf(v.y * cs4.y + sh4.y, 0.f);
                        v.z = fmaxf(v.z * cs4.z + sh4.z, 0.f);
                        v.w = fmaxf(v.w * cs4.w + sh4.w, 0.f);
                    }
                }
                float* p = As + r * 33 + c4 * 4;
                p[0] = v.x; p[1] = v.y; p[2] = v.z; p[3] = v.w;
            }
#pragma unroll
            for (int i = 0; i < 8; i++) {
                int f4 = t + i * 128;
                int wr = f4 >> 5;
                int wc = f4 & 31;
                ((float4*)Ws)[wr * 32 + wc] = ((const float4*)(W2 + (size_t)(kc + wr) * 128))[wc];
            }
            __syncthreads();
#pragma unroll 2
            for (int k = 0; k < 32; k++) {
                float4 bb0 = *(const float4*)(Ws + k * 128 + cA);
                float4 bb1 = *(const float4*)(Ws + k * 128 + cB);
                float bv[8] = {bb0.x, bb0.y, bb0.z, bb0.w, bb1.x, bb1.y, bb1.z, bb1.w};
#pragma unroll
                for (int j = 0; j < 8; j++) {
                    float a = As[(row0r + j) * 33 + k];
#pragma unroll
                    for (int c = 0; c < 8; c++) acc[j][c] += a * bv[c];
                }
            }
            __syncthreads();
        }
        float4 c0 = *(const float4*)(b1 + cA);
        float4 c1 = *(const float4*)(b1 + cB);
        float bv2[8] = {c0.x, c0.y, c0.z, c0.w, c1.x, c1.y, c1.z, c1.w};
#pragma unroll
        for (int j = 0; j < 8; j++)
#pragma unroll
            for (int c = 0; c < 8; c++) out[j][c] = acc[j][c] + bv2[c];
    }

    // =================== store + stats ===================
    float psum[8] = {0,0,0,0,0,0,0,0};
    float psq[8]  = {0,0,0,0,0,0,0,0};
#pragma unroll
    for (int j = 0; j < 8; j++) {
        int grow = row0 + row0r + j;
        if (grow >= M) continue;
        if (STATS) {
#pragma unroll
            for (int c = 0; c < 8; c++) { psum[c] += out[j][c]; psq[c] += out[j][c] * out[j][c]; }
        }
        *(float4*)(C + (size_t)grow * 128 + cA) = make_float4(out[j][0], out[j][1], out[j][2], out[j][3]);
        *(float4*)(C + (size_t)grow * 128 + cB) = make_float4(out[j][4], out[j][5], out[j][6], out[j][7]);
    }

    if (STATS) {
        float* red = As;   // 8 x 129 = 1032 floats (pad 129 -> ~2-way max)
        __syncthreads();
#pragma unroll
        for (int c = 0; c < 4; c++) red[rowg * 129 + cA + c] = psum[c];
#pragma unroll
        for (int c = 0; c < 4; c++) red[rowg * 129 + cB + c] = psum[4 + c];
        __syncthreads();
        if (t < 128) {
            float s = 0.f;
#pragma unroll
            for (int r = 0; r < 8; r++) s += red[r * 129 + t];
            atomicAdd(&stats[t], s);
        }
        __syncthreads();
#pragma unroll
        for (int c = 0; c < 4; c++) red[rowg * 129 + cA + c] = psq[c];
#pragma unroll
        for (int c = 0; c < 4; c++) red[rowg * 129 + cB + c] = psq[4 + c];
        __syncthreads();
        if (t < 128) {
            float s = 0.f;
#pragma unroll
            for (int r = 0; r < 8; r++) s += red[r * 129 + t];
            atomicAdd(&stats[128 + t], s);
        }
    }
}

// ---------------------------------------------------------------------------
// BN finalize
// ---------------------------------------------------------------------------
__global__ void bn_finalize_kernel(const float* __restrict__ stats,
                                   const float* __restrict__ gamma,
                                   const float* __restrict__ beta,
                                   float* __restrict__ cs, float* __restrict__ sh) {
    int t = threadIdx.x;
    if (t >= 128) return;
    float inv_n = 1.0f / (float)N_NODES;
    float mu = stats[t] * inv_n;
    float var = stats[128 + t] * inv_n - mu * mu;
    float rs = rsqrtf(var + BN_EPS);
    float c = gamma[t] * rs;
    cs[t] = c;
    sh[t] = beta[t] - mu * c;
}

// ---------------------------------------------------------------------------
// global mean pool (fused BN affine + relu)
// ---------------------------------------------------------------------------
__global__ void gstart_kernel(const int* __restrict__ batch, int* __restrict__ gstart, int n) {
    int g = blockIdx.x * blockDim.x + threadIdx.x;
    if (g > N_GRAPHS) return;
    int lo = 0, hi = n;
    while (lo < hi) {
        int mid = (lo + hi) >> 1;
        if (batch[mid] < g) lo = mid + 1; else hi = mid;
    }
    gstart[g] = lo;
}

__global__ __launch_bounds__(128) void pool_mean_kernel(const float* __restrict__ h,
                                                        const int* __restrict__ gstart,
                                                        const float* __restrict__ cs,
                                                        const float* __restrict__ sh,
                                                        float* __restrict__ out) {
    int g = blockIdx.x;
    int col = threadIdx.x;
    int beg = gstart[g];
    int end = gstart[g + 1];
    float c = cs[col], b = sh[col];
    float s = 0.f;
    for (int i = beg; i < end; i++)
        s += fmaxf(h[(size_t)i * 128 + col] * c + b, 0.f);
    float cnt = fmaxf((float)(end - beg), 1.0f);
    out[(size_t)g * 128 + col] = s / cnt;
}

// ---------------------------------------------------------------------------
extern "C" void kernel_launch(void* const* d_in, const int* in_sizes, int n_in,
                              void* d_out, int out_size, void* d_ws, size_t ws_size,
                              hipStream_t stream) {
    const float* x    = (const float*)d_in[0];
    const int*   ei   = (const int*)d_in[1];
    const int*   src  = ei;
    const int*   dst  = ei + N_EDGES;
    const int*   batch = (const int*)d_in[2];
    const float* gw1  = (const float*)d_in[3];
    const float* gb1  = (const float*)d_in[4];
    const float* gw2  = (const float*)d_in[5];
    const float* gb2  = (const float*)d_in[6];
    const float* swl  = (const float*)d_in[7];
    const float* sbl  = (const float*)d_in[8];
    const float* swr  = (const float*)d_in[9];
    const float* bng  = (const float*)d_in[10];
    const float* bnb  = (const float*)d_in[11];
    float* out = (float*)d_out;

    float* ws      = (float*)d_ws;
    float* hA      = ws;                      // 6.4M
    float* hB      = ws + 6400000;            // 6.4M
    float* agg     = ws + 12800000;           // 6.4M
    float* inv_deg = ws + 19200000;           // 50000
    float* stats   = ws + 19250000;           // 3 x 256
    float* cs      = ws + 19250768;           // 3 x 128
    float* sh      = ws + 19251152;           // 3 x 128
    int*   row_beg = (int*)(ws + 19251536);   // 50000
    int*   cursor  = (int*)(ws + 19301536);   // 50000
    int*   csr_src = (int*)(ws + 19351536);   // 600000
    int*   gstart  = (int*)(ws + 19951536);   // 513
    int*   total   = (int*)(ws + 19952049);   // 1

    const int gemm_blocks = (N_NODES + 63) / 64;          // 782
    const int aggr_blocks = (N_NODES * 32 + 255) / 256;

    // ---- CSR build ----
    hipMemsetAsync(cursor, 0, N_NODES * sizeof(int), stream);
    hipMemsetAsync(total, 0, sizeof(int), stream);
    hipMemsetAsync(stats, 0, 3 * 256 * sizeof(float), stream);
    deg_count_kernel<<<(N_EDGES + 255) / 256, 256, 0, stream>>>(dst, cursor, N_EDGES);
    alloc_kernel<<<(N_NODES + 255) / 256, 256, 0, stream>>>(cursor, row_beg, inv_deg, total, N_NODES);
    csr_fill_kernel<<<(N_EDGES + 255) / 256, 256, 0, stream>>>(src, dst, cursor, csr_src, N_EDGES);
    gstart_kernel<<<3, 256, 0, stream>>>(batch, gstart, N_NODES);

    // ---- GIN (fused two GEMMs) ----
    csr_aggregate_kernel<false><<<aggr_blocks, 256, 0, stream>>>(
        x, row_beg, cursor, csr_src, nullptr, nullptr, agg, N_NODES);
    gemm_tile_kernel<0, true, false><<<gemm_blocks, 128, 0, stream>>>(
        x, agg, gw1, gw2, gb1, gb2, nullptr, nullptr, nullptr, stats + 0, hB, N_NODES);
    bn_finalize_kernel<<<1, 128, 0, stream>>>(stats + 0, bng + 0 * HID, bnb + 0 * HID, cs + 0, sh + 0);

    // ---- SAGE 0 ----
    csr_aggregate_kernel<true><<<aggr_blocks, 256, 0, stream>>>(
        hB, row_beg, cursor, csr_src, cs + 0, sh + 0, agg, N_NODES);
    gemm_tile_kernel<2, true, true><<<gemm_blocks, 128, 0, stream>>>(
        agg, hB, swl + 0 * HID * HID, swr + 0 * HID * HID, sbl + 0 * HID, nullptr,
        inv_deg, cs + 0, sh + 0, stats + 256, hA, N_NODES);
    bn_finalize_kernel<<<1, 128, 0, stream>>>(stats + 256, bng + 1 * HID, bnb + 1 * HID, cs + 128, sh + 128);

    // ---- SAGE 1 ----
    csr_aggregate_kernel<true><<<aggr_blocks, 256, 0, stream>>>(
        hA, row_beg, cursor, csr_src, cs + 128, sh + 128, agg, N_NODES);
    gemm_tile_kernel<2, true, true><<<gemm_blocks, 128, 0, stream>>>(
        agg, hA, swl + 1 * HID * HID, swr + 1 * HID * HID, sbl + 1 * HID, nullptr,
        inv_deg, cs + 128, sh + 128, stats + 512, hB, N_NODES);
    bn_finalize_kernel<<<1, 128, 0, stream>>>(stats + 512, bng + 2 * HID, bnb + 2 * HID, cs + 256, sh + 256);

    // ---- pool ----
    pool_mean_kernel<<<N_GRAPHS, 128, 0, stream>>>(hB, gstart, cs + 256, sh + 256, out);
}